// Round 5
// baseline (249.609 us; speedup 1.0000x reference)
//
#include <hip/hip_runtime.h>
#include <hip/hip_bf16.h>

#define CC 64
#define HW 9216
#define IMG 96
#define SPLITS 8
#define SPLEN 1152            // 9216 / 8
#define ITERS 18              // 1152 / 64

typedef _Float16 f16;
typedef __attribute__((ext_vector_type(8))) _Float16 f16x8;
typedef __attribute__((ext_vector_type(4))) float f32x4;

// ---------------- dilated 3x3 conv (pad=2, dil=2): writes y (f16 flat chw = Q rows) and kt[m*64+c] (K^T)
__global__ __launch_bounds__(256) void conv_dil_kernel(
    const float* __restrict__ x, const float* __restrict__ dW, const float* __restrict__ db,
    f16* __restrict__ y, f16* __restrict__ kt)
{
    const int b = blockIdx.x;            // 8 co-groups * 36 chunks
    const int cog = b / 36, chunk = b % 36;
    const int t = threadIdx.x;
    const int m = chunk * 256 + t;
    const int h = m / IMG, w = m % IMG;

    int off[9]; float fv[9];
    #pragma unroll
    for (int kh = 0; kh < 3; ++kh)
        #pragma unroll
        for (int kw = 0; kw < 3; ++kw) {
            int hh = h + 2 * kh - 2, ww = w + 2 * kw - 2;
            bool ok = (hh >= 0 && hh < IMG && ww >= 0 && ww < IMG);
            int hc = min(max(hh, 0), IMG - 1), wc = min(max(ww, 0), IMG - 1);
            off[kh * 3 + kw] = hc * IMG + wc;
            fv[kh * 3 + kw] = ok ? 1.f : 0.f;
        }
    const int co0 = cog * 8;
    float acc[8];
    #pragma unroll
    for (int cc = 0; cc < 8; ++cc) acc[cc] = db[co0 + cc];

    for (int ci = 0; ci < CC; ++ci) {
        const float* xp = x + ci * HW;
        float tv[9];
        #pragma unroll
        for (int k = 0; k < 9; ++k) tv[k] = xp[off[k]] * fv[k];
        #pragma unroll
        for (int cc = 0; cc < 8; ++cc) {
            const float* wp = dW + (co0 + cc) * 576 + ci * 9;   // block-uniform -> s_load
            #pragma unroll
            for (int k = 0; k < 9; ++k) acc[cc] += wp[k] * tv[k];
        }
    }
    #pragma unroll
    for (int cc = 0; cc < 8; ++cc) {
        f16 hv = (f16)acc[cc];
        y[(co0 + cc) * HW + m] = hv;        // flat chw = Q layout via reinterpret
        kt[m * 64 + (co0 + cc)] = hv;       // K^T[m][c]
    }
}

// ---------------- 1x1 conv: writes vt[c][m] (transposed V-matrix, f16)
__global__ __launch_bounds__(256) void conv1x1_kernel(
    const float* __restrict__ x, const float* __restrict__ cW, const float* __restrict__ cb,
    f16* __restrict__ vt)
{
    const int b = blockIdx.x;
    const int cog = b / 36, chunk = b % 36;
    const int t = threadIdx.x;
    const int m = chunk * 256 + t;
    const int co0 = cog * 8;
    float acc[8];
    #pragma unroll
    for (int cc = 0; cc < 8; ++cc) acc[cc] = cb[co0 + cc];
    for (int ci = 0; ci < CC; ++ci) {
        float xv = x[ci * HW + m];
        #pragma unroll
        for (int cc = 0; cc < 8; ++cc)
            acc[cc] += cW[(co0 + cc) * CC + ci] * xv;
    }
    #pragma unroll
    for (int cc = 0; cc < 8; ++cc) {
        // V[row][col]: flat idx i=(co+cc)*9216+m -> row=i>>6, col=i&63; vt[col*HW+row]
        vt[(m & 63) * HW + (co0 + cc) * 144 + (m >> 6)] = (f16)acc[cc];
    }
}

// ---------------- MFMA flash attention, BM=64 rows, 8 m-splits, BN=64 per iter, all-f16 operands
__global__ __launch_bounds__(256, 4) void attn_kernel(
    const f16* __restrict__ kt, const f16* __restrict__ vt, const f16* __restrict__ y,
    f16* __restrict__ acc_ws, float* __restrict__ m_ws, float* __restrict__ l_ws)
{
    __shared__ f16 sKT[64 * 72];        // [m_local][c], row stride 144 B
    __shared__ f16 sVT[64 * 72];        // [c][m_local]
    __shared__ f16 sPS[4 * 16 * 72];    // per-wave P [row][m_local]

    const int t = threadIdx.x;
    const int L = t & 63, w = t >> 6;
    const int g = L >> 4, c16 = L & 15;
    const int qb = blockIdx.x >> 3, sp = blockIdx.x & 7;
    const int n0 = qb * 64;
    const int mbase = sp * SPLEN;
    f16* psw = (f16*)sPS + w * 16 * 72;

    // ones-column B-frag: B[k][n] = (n==0) -> lanes with c16==0 hold 1s
    const f16 onev = (c16 == 0) ? (f16)1.0f : (f16)0.0f;
    const f16x8 onesf = {onev, onev, onev, onev, onev, onev, onev, onev};

    // Q A-fragments (rows n0+16w+c16), kept in regs all kernel
    f16x8 qa[2];
    #pragma unroll
    for (int kc = 0; kc < 2; ++kc)
        qa[kc] = *(const f16x8*)(y + (n0 + w * 16 + c16) * 64 + g * 8 + kc * 32);

    float mi[4];
    f32x4 acc[4], acc_l;
    #pragma unroll
    for (int j = 0; j < 4; ++j) mi[j] = -1e30f;
    #pragma unroll
    for (int ct = 0; ct < 4; ++ct) acc[ct] = (f32x4){0.f, 0.f, 0.f, 0.f};
    acc_l = (f32x4){0.f, 0.f, 0.f, 0.f};

    for (int it = 0; it < ITERS; ++it) {
        const int m0 = mbase + it * 64;
        __syncthreads();
        // stage K^T and V^T tiles (coalesced uint4 -> padded rows)
        #pragma unroll
        for (int rep = 0; rep < 2; ++rep) {
            int idx = t + rep * 256;
            int row = idx >> 3, ch = idx & 7;
            *(uint4*)&sKT[row * 72 + ch * 8] = *(const uint4*)&kt[(m0 + row) * 64 + ch * 8];
            *(uint4*)&sVT[row * 72 + ch * 8] = *(const uint4*)&vt[row * HW + m0 + ch * 8];
        }
        __syncthreads();

        // S = Q K  (4 m-tiles of 16; D: col=c16, rows 4g+j)
        f32x4 s[4];
        #pragma unroll
        for (int mt = 0; mt < 4; ++mt) {
            f32x4 a0 = (f32x4){0.f, 0.f, 0.f, 0.f};
            #pragma unroll
            for (int kc = 0; kc < 2; ++kc) {
                f16x8 kb = *(const f16x8*)&sKT[(mt * 16 + c16) * 72 + g * 8 + kc * 32];
                a0 = __builtin_amdgcn_mfma_f32_16x16x32_f16(qa[kc], kb, a0, 0, 0, 0);
            }
            s[mt] = a0;
        }
        // threshold mask to ZERO
        #pragma unroll
        for (int mt = 0; mt < 4; ++mt)
            #pragma unroll
            for (int j = 0; j < 4; ++j)
                s[mt][j] = (fabsf(s[mt][j]) > 0.3f) ? s[mt][j] : 0.f;

        // online softmax per row (max via shfl over the 16-lane group; denominator via ones-MFMA)
        #pragma unroll
        for (int j = 0; j < 4; ++j) {
            float mx = fmaxf(fmaxf(s[0][j], s[1][j]), fmaxf(s[2][j], s[3][j]));
            mx = fmaxf(mx, __shfl_xor(mx, 1, 64));
            mx = fmaxf(mx, __shfl_xor(mx, 2, 64));
            mx = fmaxf(mx, __shfl_xor(mx, 4, 64));
            mx = fmaxf(mx, __shfl_xor(mx, 8, 64));
            float mnew = fmaxf(mi[j], mx);
            float alpha = __expf(mi[j] - mnew);
            mi[j] = mnew;
            f16 p0 = (f16)__expf(s[0][j] - mnew);
            f16 p1 = (f16)__expf(s[1][j] - mnew);
            f16 p2 = (f16)__expf(s[2][j] - mnew);
            f16 p3 = (f16)__expf(s[3][j] - mnew);
            #pragma unroll
            for (int ct = 0; ct < 4; ++ct) acc[ct][j] *= alpha;
            acc_l[j] *= alpha;
            const int prow = 4 * g + j;
            psw[prow * 72 + 0 * 16 + c16] = p0;
            psw[prow * 72 + 1 * 16 + c16] = p1;
            psw[prow * 72 + 2 * 16 + c16] = p2;
            psw[prow * 72 + 3 * 16 + c16] = p3;
        }

        // PV + denominator: A = P (A-layout from psw; same-wave LDS RAW is ordered)
        f16x8 pa[2];
        #pragma unroll
        for (int kc = 0; kc < 2; ++kc)
            pa[kc] = *(const f16x8*)&psw[c16 * 72 + g * 8 + kc * 32];
        #pragma unroll
        for (int ct = 0; ct < 4; ++ct)
            #pragma unroll
            for (int kc = 0; kc < 2; ++kc) {
                f16x8 vb = *(const f16x8*)&sVT[(ct * 16 + c16) * 72 + g * 8 + kc * 32];
                acc[ct] = __builtin_amdgcn_mfma_f32_16x16x32_f16(pa[kc], vb, acc[ct], 0, 0, 0);
            }
        #pragma unroll
        for (int kc = 0; kc < 2; ++kc)
            acc_l = __builtin_amdgcn_mfma_f32_16x16x32_f16(pa[kc], onesf, acc_l, 0, 0, 0);
    }

    // write partials (no divide; merge kernel combines splits). acc_l col0 = row sums.
    const int base = blockIdx.x;
    #pragma unroll
    for (int ct = 0; ct < 4; ++ct)
        #pragma unroll
        for (int j = 0; j < 4; ++j)
            acc_ws[base * 4096 + (w * 16 + 4 * g + j) * 64 + ct * 16 + c16] = (f16)acc[ct][j];
    if (c16 == 0) {
        #pragma unroll
        for (int j = 0; j < 4; ++j) {
            m_ws[base * 64 + w * 16 + 4 * g + j] = mi[j];
            l_ws[base * 64 + w * 16 + 4 * g + j] = acc_l[j];
        }
    }
}

// ---------------- merge splits + residual + transpose to (C, HW)
__global__ __launch_bounds__(256) void merge_kernel(
    const f16* __restrict__ acc_ws, const float* __restrict__ m_ws, const float* __restrict__ l_ws,
    const float* __restrict__ x, float* __restrict__ out)
{
    __shared__ float wsh[SPLITS * 64];
    __shared__ float att[64 * 65];
    const int qb = blockIdx.x;
    const int t = threadIdx.x;
    if (t < 64) {
        float ms = -1e30f;
        float mv[SPLITS];
        #pragma unroll
        for (int sp = 0; sp < SPLITS; ++sp) {
            mv[sp] = m_ws[(qb * SPLITS + sp) * 64 + t];
            ms = fmaxf(ms, mv[sp]);
        }
        float Lsum = 0.f, ev[SPLITS];
        #pragma unroll
        for (int sp = 0; sp < SPLITS; ++sp) {
            ev[sp] = __expf(mv[sp] - ms);
            Lsum += l_ws[(qb * SPLITS + sp) * 64 + t] * ev[sp];
        }
        float inv = 1.f / Lsum;
        #pragma unroll
        for (int sp = 0; sp < SPLITS; ++sp)
            wsh[sp * 64 + t] = ev[sp] * inv;
    }
    __syncthreads();
    for (int i = t; i < 4096; i += 256) {
        int r = i >> 6, c = i & 63;
        float v = 0.f;
        #pragma unroll
        for (int sp = 0; sp < SPLITS; ++sp)
            v += (float)acc_ws[(qb * SPLITS + sp) * 4096 + r * 64 + c] * wsh[sp * 64 + r];
        att[c * 65 + r] = v;
    }
    __syncthreads();
    const int n0 = qb * 64;
    for (int i = t; i < 4096; i += 256) {
        int c = i >> 6, r = i & 63;
        int idx = c * HW + n0 + r;
        out[idx] = x[idx] + att[c * 65 + r];
    }
}

extern "C" void kernel_launch(void* const* d_in, const int* in_sizes, int n_in,
                              void* d_out, int out_size, void* d_ws, size_t ws_size,
                              hipStream_t stream)
{
    const float* x  = (const float*)d_in[0];
    const float* dW = (const float*)d_in[1];
    const float* db = (const float*)d_in[2];
    const float* cW = (const float*)d_in[3];
    const float* cb = (const float*)d_in[4];
    float* out = (float*)d_out;

    char* ws = (char*)d_ws;
    f16* y      = (f16*)(ws);                        // 1,179,648 B
    f16* kt     = (f16*)(ws + 1179648);              // 1,179,648 B
    f16* vt     = (f16*)(ws + 2359296);              // 1,179,648 B
    f16* acc_ws = (f16*)(ws + 3538944);              // 9,437,184 B
    float* m_ws = (float*)(ws + 12976128);           //   294,912 B
    float* l_ws = (float*)(ws + 13271040);           //   294,912 B
                                                     // total 13,565,952 B (<= proven 15.6 MB)

    conv_dil_kernel<<<dim3(8 * 36), dim3(256), 0, stream>>>(x, dW, db, y, kt);
    conv1x1_kernel<<<dim3(8 * 36), dim3(256), 0, stream>>>(x, cW, cb, vt);
    attn_kernel<<<dim3(144 * SPLITS), dim3(256), 0, stream>>>(kt, vt, y, acc_ws, m_ws, l_ws);
    merge_kernel<<<dim3(144), dim3(256), 0, stream>>>(acc_ws, m_ws, l_ws, x, out);
}

// Round 6
// 182.593 us; speedup vs baseline: 1.3670x; 1.3670x over previous
//
#include <hip/hip_runtime.h>
#include <hip/hip_bf16.h>

#define CC 64
#define HW 9216
#define IMG 96
#define SPLITS 8
#define SPLEN 1152            // 9216 / 8
#define ITERS 18              // 1152 / 64

typedef _Float16 f16;
typedef __attribute__((ext_vector_type(8))) _Float16 f16x8;
typedef __attribute__((ext_vector_type(4))) float f32x4;

// ---------------- dilated 3x3 conv (pad=2, dil=2): writes y (f16 flat chw = Q rows) and kt[m*64+c] (K^T)
// co=4 per block, weights staged in LDS (broadcast reads), grid 576 for occupancy
__global__ __launch_bounds__(256) void conv_dil_kernel(
    const float* __restrict__ x, const float* __restrict__ dW, const float* __restrict__ db,
    f16* __restrict__ y, f16* __restrict__ kt)
{
    __shared__ float wsh[4 * 576];       // 9.2 KB
    const int b = blockIdx.x;            // 16 co-groups * 36 chunks
    const int cog = b / 36, chunk = b % 36;
    const int t = threadIdx.x;
    const int co0 = cog * 4;

    for (int i = t; i < 4 * 576; i += 256)
        wsh[i] = dW[co0 * 576 + i];
    __syncthreads();

    const int m = chunk * 256 + t;
    const int h = m / IMG, w = m % IMG;

    int off[9]; float fv[9];
    #pragma unroll
    for (int kh = 0; kh < 3; ++kh)
        #pragma unroll
        for (int kw = 0; kw < 3; ++kw) {
            int hh = h + 2 * kh - 2, ww = w + 2 * kw - 2;
            bool ok = (hh >= 0 && hh < IMG && ww >= 0 && ww < IMG);
            int hc = min(max(hh, 0), IMG - 1), wc = min(max(ww, 0), IMG - 1);
            off[kh * 3 + kw] = hc * IMG + wc;
            fv[kh * 3 + kw] = ok ? 1.f : 0.f;
        }

    float acc[4];
    #pragma unroll
    for (int cc = 0; cc < 4; ++cc) acc[cc] = db[co0 + cc];

    #pragma unroll 2
    for (int ci = 0; ci < CC; ++ci) {
        const float* xp = x + ci * HW;
        float tv[9];
        #pragma unroll
        for (int k = 0; k < 9; ++k) tv[k] = xp[off[k]] * fv[k];
        #pragma unroll
        for (int cc = 0; cc < 4; ++cc) {
            const float* wp = wsh + cc * 576 + ci * 9;   // lane-uniform -> LDS broadcast
            #pragma unroll
            for (int k = 0; k < 9; ++k) acc[cc] += wp[k] * tv[k];
        }
    }
    #pragma unroll
    for (int cc = 0; cc < 4; ++cc) {
        f16 hv = (f16)acc[cc];
        y[(co0 + cc) * HW + m] = hv;        // flat chw = Q layout via reinterpret
        kt[m * 64 + (co0 + cc)] = hv;       // K^T[m][c]
    }
}

// ---------------- 1x1 conv: writes vt[c][m] (transposed V-matrix, f16); co=4/block, LDS weights
__global__ __launch_bounds__(256) void conv1x1_kernel(
    const float* __restrict__ x, const float* __restrict__ cW, const float* __restrict__ cb,
    f16* __restrict__ vt)
{
    __shared__ float wsh[4 * 64];
    const int b = blockIdx.x;            // 16 co-groups * 36 chunks
    const int cog = b / 36, chunk = b % 36;
    const int t = threadIdx.x;
    const int co0 = cog * 4;
    if (t < 256 && t < 4 * 64) wsh[t] = cW[co0 * CC + t];
    __syncthreads();

    const int m = chunk * 256 + t;
    float acc[4];
    #pragma unroll
    for (int cc = 0; cc < 4; ++cc) acc[cc] = cb[co0 + cc];
    #pragma unroll 4
    for (int ci = 0; ci < CC; ++ci) {
        float xv = x[ci * HW + m];
        #pragma unroll
        for (int cc = 0; cc < 4; ++cc)
            acc[cc] += wsh[cc * 64 + ci] * xv;
    }
    #pragma unroll
    for (int cc = 0; cc < 4; ++cc) {
        // V[row][col]: flat idx i=(co+cc)*9216+m -> row=i>>6, col=i&63; vt[col*HW+row]
        vt[(m & 63) * HW + (co0 + cc) * 144 + (m >> 6)] = (f16)acc[cc];
    }
}

// ---------------- MFMA flash attention, BM=64 rows, 8 m-splits, BN=64 per iter, all-f16 operands
__global__ __launch_bounds__(256, 4) void attn_kernel(
    const f16* __restrict__ kt, const f16* __restrict__ vt, const f16* __restrict__ y,
    f16* __restrict__ acc_ws, float* __restrict__ m_ws, float* __restrict__ l_ws)
{
    __shared__ f16 sKT[64 * 72];        // [m_local][c], row stride 144 B
    __shared__ f16 sVT[64 * 72];        // [c][m_local]
    __shared__ f16 sPS[4 * 16 * 72];    // per-wave P [row][m_local]

    const int t = threadIdx.x;
    const int L = t & 63, w = t >> 6;
    const int g = L >> 4, c16 = L & 15;
    const int qb = blockIdx.x >> 3, sp = blockIdx.x & 7;
    const int n0 = qb * 64;
    const int mbase = sp * SPLEN;
    f16* psw = (f16*)sPS + w * 16 * 72;

    // ones-column B-frag: B[k][n] = (n==0) -> lanes with c16==0 hold 1s
    const f16 onev = (c16 == 0) ? (f16)1.0f : (f16)0.0f;
    const f16x8 onesf = {onev, onev, onev, onev, onev, onev, onev, onev};

    // Q A-fragments (rows n0+16w+c16), kept in regs all kernel
    f16x8 qa[2];
    #pragma unroll
    for (int kc = 0; kc < 2; ++kc)
        qa[kc] = *(const f16x8*)(y + (n0 + w * 16 + c16) * 64 + g * 8 + kc * 32);

    float mi[4];
    f32x4 acc[4], acc_l;
    #pragma unroll
    for (int j = 0; j < 4; ++j) mi[j] = -1e30f;
    #pragma unroll
    for (int ct = 0; ct < 4; ++ct) acc[ct] = (f32x4){0.f, 0.f, 0.f, 0.f};
    acc_l = (f32x4){0.f, 0.f, 0.f, 0.f};

    for (int it = 0; it < ITERS; ++it) {
        const int m0 = mbase + it * 64;
        __syncthreads();
        // stage K^T and V^T tiles (coalesced uint4 -> padded rows)
        #pragma unroll
        for (int rep = 0; rep < 2; ++rep) {
            int idx = t + rep * 256;
            int row = idx >> 3, ch = idx & 7;
            *(uint4*)&sKT[row * 72 + ch * 8] = *(const uint4*)&kt[(m0 + row) * 64 + ch * 8];
            *(uint4*)&sVT[row * 72 + ch * 8] = *(const uint4*)&vt[row * HW + m0 + ch * 8];
        }
        __syncthreads();

        // S = Q K  (4 m-tiles of 16; D: col=c16, rows 4g+j)
        f32x4 s[4];
        #pragma unroll
        for (int mt = 0; mt < 4; ++mt) {
            f32x4 a0 = (f32x4){0.f, 0.f, 0.f, 0.f};
            #pragma unroll
            for (int kc = 0; kc < 2; ++kc) {
                f16x8 kb = *(const f16x8*)&sKT[(mt * 16 + c16) * 72 + g * 8 + kc * 32];
                a0 = __builtin_amdgcn_mfma_f32_16x16x32_f16(qa[kc], kb, a0, 0, 0, 0);
            }
            s[mt] = a0;
        }
        // threshold mask to ZERO
        #pragma unroll
        for (int mt = 0; mt < 4; ++mt)
            #pragma unroll
            for (int j = 0; j < 4; ++j)
                s[mt][j] = (fabsf(s[mt][j]) > 0.3f) ? s[mt][j] : 0.f;

        // online softmax per row (max via shfl over the 16-lane group; denominator via ones-MFMA)
        #pragma unroll
        for (int j = 0; j < 4; ++j) {
            float mx = fmaxf(fmaxf(s[0][j], s[1][j]), fmaxf(s[2][j], s[3][j]));
            mx = fmaxf(mx, __shfl_xor(mx, 1, 64));
            mx = fmaxf(mx, __shfl_xor(mx, 2, 64));
            mx = fmaxf(mx, __shfl_xor(mx, 4, 64));
            mx = fmaxf(mx, __shfl_xor(mx, 8, 64));
            float mnew = fmaxf(mi[j], mx);
            float alpha = __expf(mi[j] - mnew);
            mi[j] = mnew;
            f16 p0 = (f16)__expf(s[0][j] - mnew);
            f16 p1 = (f16)__expf(s[1][j] - mnew);
            f16 p2 = (f16)__expf(s[2][j] - mnew);
            f16 p3 = (f16)__expf(s[3][j] - mnew);
            #pragma unroll
            for (int ct = 0; ct < 4; ++ct) acc[ct][j] *= alpha;
            acc_l[j] *= alpha;
            const int prow = 4 * g + j;
            psw[prow * 72 + 0 * 16 + c16] = p0;
            psw[prow * 72 + 1 * 16 + c16] = p1;
            psw[prow * 72 + 2 * 16 + c16] = p2;
            psw[prow * 72 + 3 * 16 + c16] = p3;
        }

        // PV + denominator: A = P (A-layout from psw; same-wave LDS RAW is ordered)
        f16x8 pa[2];
        #pragma unroll
        for (int kc = 0; kc < 2; ++kc)
            pa[kc] = *(const f16x8*)&psw[c16 * 72 + g * 8 + kc * 32];
        #pragma unroll
        for (int ct = 0; ct < 4; ++ct)
            #pragma unroll
            for (int kc = 0; kc < 2; ++kc) {
                f16x8 vb = *(const f16x8*)&sVT[(ct * 16 + c16) * 72 + g * 8 + kc * 32];
                acc[ct] = __builtin_amdgcn_mfma_f32_16x16x32_f16(pa[kc], vb, acc[ct], 0, 0, 0);
            }
        #pragma unroll
        for (int kc = 0; kc < 2; ++kc)
            acc_l = __builtin_amdgcn_mfma_f32_16x16x32_f16(pa[kc], onesf, acc_l, 0, 0, 0);
    }

    // write partials (no divide; merge kernel combines splits). acc_l col0 = row sums.
    const int base = blockIdx.x;
    #pragma unroll
    for (int ct = 0; ct < 4; ++ct)
        #pragma unroll
        for (int j = 0; j < 4; ++j)
            acc_ws[base * 4096 + (w * 16 + 4 * g + j) * 64 + ct * 16 + c16] = (f16)acc[ct][j];
    if (c16 == 0) {
        #pragma unroll
        for (int j = 0; j < 4; ++j) {
            m_ws[base * 64 + w * 16 + 4 * g + j] = mi[j];
            l_ws[base * 64 + w * 16 + 4 * g + j] = acc_l[j];
        }
    }
}

// ---------------- merge splits + residual + transpose to (C, HW)
__global__ __launch_bounds__(256) void merge_kernel(
    const f16* __restrict__ acc_ws, const float* __restrict__ m_ws, const float* __restrict__ l_ws,
    const float* __restrict__ x, float* __restrict__ out)
{
    __shared__ float wsh[SPLITS * 64];
    __shared__ float att[64 * 65];
    const int qb = blockIdx.x;
    const int t = threadIdx.x;
    if (t < 64) {
        float ms = -1e30f;
        float mv[SPLITS];
        #pragma unroll
        for (int sp = 0; sp < SPLITS; ++sp) {
            mv[sp] = m_ws[(qb * SPLITS + sp) * 64 + t];
            ms = fmaxf(ms, mv[sp]);
        }
        float Lsum = 0.f, ev[SPLITS];
        #pragma unroll
        for (int sp = 0; sp < SPLITS; ++sp) {
            ev[sp] = __expf(mv[sp] - ms);
            Lsum += l_ws[(qb * SPLITS + sp) * 64 + t] * ev[sp];
        }
        float inv = 1.f / Lsum;
        #pragma unroll
        for (int sp = 0; sp < SPLITS; ++sp)
            wsh[sp * 64 + t] = ev[sp] * inv;
    }
    __syncthreads();
    for (int i = t; i < 4096; i += 256) {
        int r = i >> 6, c = i & 63;
        float v = 0.f;
        #pragma unroll
        for (int sp = 0; sp < SPLITS; ++sp)
            v += (float)acc_ws[(qb * SPLITS + sp) * 4096 + r * 64 + c] * wsh[sp * 64 + r];
        att[c * 65 + r] = v;
    }
    __syncthreads();
    const int n0 = qb * 64;
    for (int i = t; i < 4096; i += 256) {
        int c = i >> 6, r = i & 15 | ((i >> 4) & 3) * 16;  // = i & 63 reordered; keep simple below
        (void)r;
        int rr = i & 63;
        int idx = c * HW + n0 + rr;
        out[idx] = x[idx] + att[c * 65 + rr];
    }
}

extern "C" void kernel_launch(void* const* d_in, const int* in_sizes, int n_in,
                              void* d_out, int out_size, void* d_ws, size_t ws_size,
                              hipStream_t stream)
{
    const float* x  = (const float*)d_in[0];
    const float* dW = (const float*)d_in[1];
    const float* db = (const float*)d_in[2];
    const float* cW = (const float*)d_in[3];
    const float* cb = (const float*)d_in[4];
    float* out = (float*)d_out;

    char* ws = (char*)d_ws;
    f16* y      = (f16*)(ws);                        // 1,179,648 B
    f16* kt     = (f16*)(ws + 1179648);              // 1,179,648 B
    f16* vt     = (f16*)(ws + 2359296);              // 1,179,648 B
    f16* acc_ws = (f16*)(ws + 3538944);              // 9,437,184 B
    float* m_ws = (float*)(ws + 12976128);           //   294,912 B
    float* l_ws = (float*)(ws + 13271040);           //   294,912 B
                                                     // total 13,565,952 B

    conv_dil_kernel<<<dim3(16 * 36), dim3(256), 0, stream>>>(x, dW, db, y, kt);
    conv1x1_kernel<<<dim3(16 * 36), dim3(256), 0, stream>>>(x, cW, cb, vt);
    attn_kernel<<<dim3(144 * SPLITS), dim3(256), 0, stream>>>(kt, vt, y, acc_ws, m_ws, l_ws);
    merge_kernel<<<dim3(144), dim3(256), 0, stream>>>(acc_ws, m_ws, l_ws, x, out);
}